// Round 7
// baseline (306.579 us; speedup 1.0000x reference)
//
#include <hip/hip_runtime.h>
#include <hip/hip_bf16.h>
#include <math.h>

#define SEQ   3072
#define DIM   1280
#define NH    16
#define HD    80
#define QKV_N 3840

typedef unsigned short u16;
typedef unsigned int   u32;
typedef __attribute__((ext_vector_type(8))) short short8;   // 8 bf16 (4 VGPR)
typedef __attribute__((ext_vector_type(4))) short short4v;  // 4 bf16 (2 VGPR)
typedef __attribute__((ext_vector_type(4))) float f32x4;    // MFMA accumulator

#if defined(__has_builtin)
#  if __has_builtin(__builtin_amdgcn_mfma_f32_16x16x16bf16_1k)
#    define MFMA16(a,b,c) __builtin_amdgcn_mfma_f32_16x16x16bf16_1k(a,b,c,0,0,0)
#  endif
#endif
#ifndef MFMA16
__device__ __forceinline__ f32x4 mfma16_asm(short4v a, short4v b, f32x4 c) {
    f32x4 d;
    asm volatile("v_mfma_f32_16x16x16_bf16 %0, %1, %2, %3"
                 : "=v"(d) : "v"(a), "v"(b), "0"(c));
    return d;
}
#  define MFMA16(a,b,c) mfma16_asm(a,b,c)
#endif

// ---------------------------------------------------------------------------
// f32 -> bf16 (RTNE) and hi/lo split
// ---------------------------------------------------------------------------
__device__ __forceinline__ u16 f32_to_bf16(float x) {
    unsigned xb = __float_as_uint(x);
    return (u16)((xb + 0x7fffu + ((xb >> 16) & 1u)) >> 16);
}
__device__ __forceinline__ void split1(float x, u16& h, u16& l) {
    h = f32_to_bf16(x);
    float hf = __uint_as_float(((unsigned)h) << 16);
    l = f32_to_bf16(x - hf);
}
__device__ __forceinline__ u32 pack2(float a, float b) {
    return (u32)f32_to_bf16(a) | ((u32)f32_to_bf16(b) << 16);
}

__device__ __forceinline__ void gload16(const void* g, void* l) {
    __builtin_amdgcn_global_load_lds(
        (const __attribute__((address_space(1))) void*)g,
        (__attribute__((address_space(3))) void*)l, 16, 0, 0);
}

// ---------------------------------------------------------------------------
// split_rows: f32[n] -> hi bf16[n], lo bf16[n]
// ---------------------------------------------------------------------------
__global__ __launch_bounds__(256) void split_rows(const float* __restrict__ in,
                                                  u16* __restrict__ oh,
                                                  u16* __restrict__ ol, int n4) {
    int i = blockIdx.x * 256 + threadIdx.x;
    int stride = gridDim.x * 256;
    for (; i < n4; i += stride) {
        float4 v = ((const float4*)in)[i];
        ushort4 h, l;
        split1(v.x, h.x, l.x); split1(v.y, h.y, l.y);
        split1(v.z, h.z, l.z); split1(v.w, h.w, l.w);
        ((ushort4*)oh)[i] = h; ((ushort4*)ol)[i] = l;
    }
}

// ---------------------------------------------------------------------------
// transpose_w: in f32 [K][N] -> o bf16 [N][K]  (hi only)
// ---------------------------------------------------------------------------
__global__ __launch_bounds__(256) void transpose_w(const float* __restrict__ in,
                                                   u16* __restrict__ o,
                                                   int K, int N) {
    __shared__ float t[32][33];
    const int n0 = blockIdx.x * 32, k0 = blockIdx.y * 32;
    const int tx = threadIdx.x & 31, ty = threadIdx.x >> 5;  // 32 x 8
    #pragma unroll
    for (int j = 0; j < 4; j++)
        t[ty + j * 8][tx] = in[(size_t)(k0 + ty + j * 8) * N + n0 + tx];
    __syncthreads();
    #pragma unroll
    for (int j = 0; j < 4; j++)
        o[(size_t)(n0 + ty + j * 8) * K + k0 + tx] = f32_to_bf16(t[tx][ty + j * 8]);
}

// ---------------------------------------------------------------------------
// Fused MFMA GEMM: C = (Ah[+Al]) @ Bh^T + bias.
// 128x128 tile, BK=32, 4 waves, LDS dbuf 2x24KB, proven 2-phase sync.
// Per-block stream count: bn < bn_q -> 2-stream (Ah+Al), else 1-stream.
// Output: bn < bn_f32 -> f32 to Cf (stride ldc); else transposed bf16 to
// Vt[col - bn_f32*128][row]  (row-contiguous short4v stores).
// 1-D grid, bijective XCD-chunked swizzle, bm-major.
// ---------------------------------------------------------------------------
__global__ __launch_bounds__(256) void gemm_fused(const u16* __restrict__ Ah,
                                                  const u16* __restrict__ Al,
                                                  const u16* __restrict__ Bh,
                                                  const float* __restrict__ bias,
                                                  float* __restrict__ Cf, int ldc,
                                                  u16* __restrict__ Vt,
                                                  int bn_q, int bn_f32,
                                                  int nbn, int M, int N, int K) {
    __shared__ u16 lds[2][12288];   // per buf: Ah | Al | Bh planes, 8 KB each
    const int tid  = threadIdx.x;
    const int lane = tid & 63;
    const int w    = tid >> 6;

    // bijective XCD swizzle
    const int nwg = gridDim.x;
    const int qd  = nwg >> 3, rm = nwg & 7;
    const int xcd = blockIdx.x & 7, idx = blockIdx.x >> 3;
    const int wg  = (xcd < rm ? xcd * (qd + 1) : rm * (qd + 1) + (xcd - rm) * qd) + idx;
    const int bm = wg / nbn, bn = wg - bm * nbn;
    const int wm = w >> 1, wn = w & 1;
    const bool lo = (bn < bn_q);

    const int rl   = lane >> 2;                      // row within 16-row seg
    const int slot = lane & 3;
    const int ks   = (slot ^ ((rl >> 1) & 3)) * 8;   // swizzled k elem offset

    // staging chunks: 2-stream: 24 chunks (Ah|Al|Bh), 6/wave;
    //                 1-stream: 16 chunks (Ah|Bh),    4/wave.
    const u16* pb[3] = { Ah + (size_t)(bm * 128) * K,
                         lo ? Al + (size_t)(bm * 128) * K : Ah,
                         Bh + (size_t)(bn * 128) * K };
    const int nc = lo ? 6 : 4;
    const u16* csrc[6];
    int cdst[6];
    for (int i = 0; i < nc; i++) {
        int c = w * nc + i;
        int p = lo ? (c >> 3) : ((c >> 3) ? 2 : 0);
        int seg = c & 7;
        csrc[i] = pb[p] + (size_t)(seg * 16 + rl) * K + ks;
        cdst[i] = p * 4096 + seg * 512;              // u16 index
    }

    const f32x4 zero = {0.f, 0.f, 0.f, 0.f};
    f32x4 acc[4][4];
    #pragma unroll
    for (int i = 0; i < 4; i++)
        #pragma unroll
        for (int j = 0; j < 4; j++) acc[i][j] = zero;

    const int r16 = lane & 15, kg = lane >> 4;
    const int sw  = (kg ^ ((r16 >> 1) & 3)) * 16;    // swizzled byte slot for reads

    const int nt = K >> 5;   // BK=32 steps

    // prologue: stage tile 0 into buf 0
    for (int i = 0; i < nc; i++)
        gload16(csrc[i], &lds[0][cdst[i]]);
    __syncthreads();

    int cur = 0;
    for (int t = 0; t < nt; t++) {
        if (t + 1 < nt) {                 // prefetch next tile into other buffer
            for (int i = 0; i < nc; i++)
                gload16(csrc[i] + (t + 1) * 32, &lds[cur ^ 1][cdst[i]]);
        }

        const char* ldsb = (const char*)&lds[cur][0];
        short8 ah[4], al[4], bh[4];
        #pragma unroll
        for (int i = 0; i < 4; i++) {
            int offA = (wm * 64 + i * 16 + r16) * 64 + sw;
            ah[i] = *(const short8*)(ldsb + offA);
            if (lo) al[i] = *(const short8*)(ldsb + 8192 + offA);
            int offB = (wn * 64 + i * 16 + r16) * 64 + sw;
            bh[i] = *(const short8*)(ldsb + 16384 + offB);
        }
        #pragma unroll
        for (int i = 0; i < 4; i++)
            #pragma unroll
            for (int j = 0; j < 4; j++) {
                acc[i][j] = __builtin_amdgcn_mfma_f32_16x16x32_bf16(ah[i], bh[j], acc[i][j], 0, 0, 0);
                if (lo)
                    acc[i][j] = __builtin_amdgcn_mfma_f32_16x16x32_bf16(al[i], bh[j], acc[i][j], 0, 0, 0);
            }

        __syncthreads();   // drains vmcnt + lgkm; gates buffer swap
        cur ^= 1;
    }

    const int rg = lane >> 4;
    #pragma unroll
    for (int j = 0; j < 4; j++) {
        int col = bn * 128 + wn * 64 + j * 16 + r16;
        float bv = bias[col];
        #pragma unroll
        for (int i = 0; i < 4; i++) {
            int row0 = bm * 128 + wm * 64 + i * 16 + rg * 4;
            if (bn < bn_f32) {
                #pragma unroll
                for (int r = 0; r < 4; r++)
                    Cf[(size_t)(row0 + r) * ldc + col] = acc[i][j][r] + bv;
            } else {
                // V region: write transposed bf16 Vt[vcol][row], 4 rows contiguous
                int vcol = col - bn_f32 * 128;
                short4v hv;
                #pragma unroll
                for (int r = 0; r < 4; r++)
                    hv[r] = (short)f32_to_bf16(acc[i][j][r] + bv);
                *(short4v*)(Vt + (size_t)vcol * M + row0) = hv;
            }
        }
    }
}

// ---------------------------------------------------------------------------
// rope_split_qk: qk f32 [S][2560] + rope -> Qh/Ql (scaled by 1/sqrt(80)),
// Kh bf16 [S][1280]
// ---------------------------------------------------------------------------
__global__ __launch_bounds__(256) void rope_split_qk(const float* __restrict__ qk,
                                                     const float* __restrict__ rope,
                                                     u16* __restrict__ Qh, u16* __restrict__ Ql,
                                                     u16* __restrict__ Kh) {
    __shared__ float cs[40], sn[40];
    const int s = blockIdx.x;
    if (threadIdx.x < 40) {
        float f = rope[(size_t)s * 40 + threadIdx.x];
        cs[threadIdx.x] = cosf(f);
        sn[threadIdx.x] = sinf(f);
    }
    __syncthreads();
    const float qs = 0.11180339887498949f;   // 1/sqrt(80)
    const size_t ib = (size_t)s * 2560;
    const size_t ob = (size_t)s * DIM;
    for (int p = threadIdx.x; p < 640; p += 256) {
        int hh = p / 40, j = p - hh * 40;
        float c = cs[j], sv = sn[j];
        int e0 = hh * 80 + j, e1 = e0 + 40;
        float a0 = qk[ib + e0], a1 = qk[ib + e1];
        u16 x, y;
        split1((a0 * c - a1 * sv) * qs, x, y); Qh[ob + e0] = x; Ql[ob + e0] = y;
        split1((a1 * c + a0 * sv) * qs, x, y); Qh[ob + e1] = x; Ql[ob + e1] = y;
        float b0 = qk[ib + 1280 + e0], b1 = qk[ib + 1280 + e1];
        Kh[ob + e0] = f32_to_bf16(b0 * c - b1 * sv);
        Kh[ob + e1] = f32_to_bf16(b1 * c + b0 * sv);
    }
}

// ---------------------------------------------------------------------------
// MFMA flash attention v3: QBLK=128, 8 waves (512 thr).
//  - swapped QK^T: acc[key][q]; softmax in-register (lane owns q-row r16)
//  - PV via 16x16x16 MFMA with packed-P B-frag (no cross-lane P movement)
//  - global_load_lds staging (3 chunks/wave), dbuf, counted vmcnt(3)
//  - K/V staged once per 128 q-rows (2x reuse vs QBLK=64)
// ---------------------------------------------------------------------------
__global__ __launch_bounds__(512) void attn_mfma3(const u16* __restrict__ Qh,
                                                  const u16* __restrict__ Ql,
                                                  const u16* __restrict__ Kh,
                                                  const u16* __restrict__ Vt,
                                                  const int* __restrict__ cu,
                                                  u16* __restrict__ Oh) {
    __shared__ u16 lds[2][12288];   // per buf: K [64][80] =10240B, V [80][80]+slack
    const int tid  = threadIdx.x;
    const int lane = tid & 63;
    const int w    = tid >> 6;       // 0..7
    const int r16  = lane & 15;
    const int kg   = lane >> 4;
    const int h    = blockIdx.x;
    const int q0   = blockIdx.y * 128;

    int kstart, kend;
    {
        int c1 = cu[1], c2 = cu[2], c3 = cu[3];
        if      (q0 < c1) { kstart = cu[0]; kend = c1; }
        else if (q0 < c2) { kstart = c1;    kend = c2; }
        else if (q0 < c3) { kstart = c2;    kend = c3; }
        else              { kstart = c3;    kend = cu[4]; }
    }

    // per-lane global staging sources: 3 chunks (1 KB each) per wave, 24 total
    const char* cbase[3];
    int cscale[3];
    #pragma unroll
    for (int i = 0; i < 3; i++) {
        int c = w * 3 + i;
        if (c < 10) {                        // K plane: [64 rows][160 B]
            int o = c * 1024 + lane * 16;
            int row = o / 160, col = o - row * 160;
            cbase[i]  = (const char*)Kh + (size_t)row * 2560 + h * 160 + col;
            cscale[i] = 2560;                // + k0 rows
        } else {                             // V plane: [80 rows][160 B] + slack
            int o = (c - 10) * 1024 + lane * 16;
            int row = o / 160, col = o - row * 160;
            if (row > 79) row = 79;          // slack lanes: clamp to a safe row
            cbase[i]  = (const char*)Vt + (size_t)(h * HD + row) * (SEQ * 2) + col;
            cscale[i] = 2;                   // + k0 elems
        }
    }

    // Q fragments (pre-scaled); B-operand of swapped QK^T
    const short8 z8 = {0, 0, 0, 0, 0, 0, 0, 0};
    short8 qfh[3], qfl[3];
    {
        const size_t qb = (size_t)(q0 + w * 16 + r16) * DIM + h * HD;
        #pragma unroll
        for (int ks = 0; ks < 3; ks++) {
            int ko = ks * 32 + kg * 8;
            if (ko < HD) {
                qfh[ks] = *(const short8*)(Qh + qb + ko);
                qfl[ks] = *(const short8*)(Ql + qb + ko);
            } else { qfh[ks] = z8; qfl[ks] = z8; }
        }
    }

    const f32x4 zf = {0.f, 0.f, 0.f, 0.f};
    f32x4 acc_o[5] = {zf, zf, zf, zf, zf};   // O^T: lane q-row = r16, d = db*16+kg*4+r
    float m_ = -3.0e38f, l_ = 0.f;

    // prologue stage of first tile
    {
        char* dst = (char*)&lds[0][0] + (w * 3) * 1024;
        #pragma unroll
        for (int i = 0; i < 3; i++)
            gload16(cbase[i] + (size_t)kstart * cscale[i], dst + i * 1024);
    }

    int cur = 0;
    for (int k0 = kstart; k0 < kend; k0 += 64) {
        if (k0 + 64 < kend) {                // prefetch next tile into other buffer
            char* dst = (char*)&lds[cur ^ 1][0] + (w * 3) * 1024;
            #pragma unroll
            for (int i = 0; i < 3; i++)
                gload16(cbase[i] + (size_t)(k0 + 64) * cscale[i], dst + i * 1024);
            __builtin_amdgcn_sched_barrier(0);
            asm volatile("s_waitcnt vmcnt(3)");   // drain current tile, keep 3 in flight
        } else {
            __builtin_amdgcn_sched_barrier(0);
            asm volatile("s_waitcnt vmcnt(0)");
        }
        __builtin_amdgcn_s_barrier();
        __builtin_amdgcn_sched_barrier(0);

        const char* bK = (const char*)&lds[cur][0];
        const char* bV = bK + 10240;

        // ---- QK^T (swapped): accs[kb] = C[key-sub][q=r16], key = kb*16+kg*4+r
        f32x4 accs[4] = {zf, zf, zf, zf};
        #pragma unroll
        for (int kb = 0; kb < 4; kb++) {
            #pragma unroll
            for (int ks = 0; ks < 3; ks++) {
                short8 af = *(const short8*)(bK + (kb * 16 + r16) * 160 + ks * 64 + kg * 16);
                accs[kb] = __builtin_amdgcn_mfma_f32_16x16x32_bf16(af, qfh[ks], accs[kb], 0, 0, 0);
                accs[kb] = __builtin_amdgcn_mfma_f32_16x16x32_bf16(af, qfl[ks], accs[kb], 0, 0, 0);
            }
        }

        // ---- online softmax (scores pre-scaled); lane owns q-row r16
        float tmax = -3.0e38f;
        #pragma unroll
        for (int kb = 0; kb < 4; kb++)
            tmax = fmaxf(tmax, fmaxf(fmaxf(accs[kb][0], accs[kb][1]),
                                     fmaxf(accs[kb][2], accs[kb][3])));
        tmax = fmaxf(tmax, __shfl_xor(tmax, 16, 64));
        tmax = fmaxf(tmax, __shfl_xor(tmax, 32, 64));
        float mn = fmaxf(m_, tmax);
        float al = __expf(m_ - mn);
        float lt = 0.f;
        u32 pk[4][2];
        #pragma unroll
        for (int kb = 0; kb < 4; kb++) {
            float p0 = __expf(accs[kb][0] - mn);
            float p1 = __expf(accs[kb][1] - mn);
            float p2 = __expf(accs[kb][2] - mn);
            float p3 = __expf(accs[kb][3] - mn);
            lt += (p0 + p1) + (p2 + p3);
            pk[kb][0] = pack2(p0, p1);
            pk[kb][1] = pack2(p2, p3);
        }
        lt += __shfl_xor(lt, 16, 64);
        lt += __shfl_xor(lt, 32, 64);
        l_ = l_ * al + lt;
        m_ = mn;
        #pragma unroll
        for (int db = 0; db < 5; db++) acc_o[db] *= al;

        // ---- PV (16x16x16): A = Vt rows (d), B = packed P (direct reg reuse)
        #pragma unroll
        for (int kb = 0; kb < 4; kb++) {
            union { u32 u[2]; short4v s; } cv;
            cv.u[0] = pk[kb][0]; cv.u[1] = pk[kb][1];
            short4v pb = cv.s;
            #pragma unroll
            for (int db = 0; db < 5; db++) {
                short4v vf = *(const short4v*)(bV + (db * 16 + r16) * 160 + kb * 32 + kg * 8);
                acc_o[db] = MFMA16(vf, pb, acc_o[db]);
            }
        }

        __builtin_amdgcn_s_barrier();        // all reads of buf[cur] done
        __builtin_amdgcn_sched_barrier(0);
        cur ^= 1;
    }

    // ---- epilogue: O^T -> Oh [S][1280]; lane q-row = r16 (hi plane only)
    float inv = 1.0f / l_;
    const size_t ob = (size_t)(q0 + w * 16 + r16) * DIM + h * HD + kg * 4;
    #pragma unroll
    for (int db = 0; db < 5; db++) {
        short4v hv;
        #pragma unroll
        for (int r = 0; r < 4; r++)
            hv[r] = (short)f32_to_bf16(acc_o[db][r] * inv);
        *(short4v*)(Oh + ob + db * 16) = hv;
    }
}

// ---------------------------------------------------------------------------
// f32 fallback path (round-1, known-good)
// ---------------------------------------------------------------------------
__global__ __launch_bounds__(256) void sgemm_bias(const float* __restrict__ A,
                                                  const float* __restrict__ B,
                                                  const float* __restrict__ bias,
                                                  float* __restrict__ C,
                                                  int M, int N, int K) {
    __shared__ float As[8][128];
    __shared__ float Bs[8][128];
    const int tid = threadIdx.x;
    const int tx  = tid & 15;
    const int ty  = tid >> 4;
    const int bx  = blockIdx.x, by = blockIdx.y;
    const int row_a = tid >> 1;
    const int col_a = (tid & 1) * 4;
    const int row_b = tid >> 5;
    const int col_b = (tid & 31) * 4;
    const float* Ap = A + (size_t)(by * 128 + row_a) * K + col_a;
    const float* Bp = B + (size_t)row_b * N + bx * 128 + col_b;
    float acc[8][8];
    #pragma unroll
    for (int i = 0; i < 8; i++)
        #pragma unroll
        for (int j = 0; j < 8; j++) acc[i][j] = 0.f;
    for (int k0 = 0; k0 < K; k0 += 8) {
        float4 av = *(const float4*)(Ap + k0);
        float4 bv = *(const float4*)(Bp + (size_t)k0 * N);
        __syncthreads();
        As[col_a + 0][row_a] = av.x; As[col_a + 1][row_a] = av.y;
        As[col_a + 2][row_a] = av.z; As[col_a + 3][row_a] = av.w;
        *(float4*)&Bs[row_b][col_b] = bv;
        __syncthreads();
        #pragma unroll
        for (int kk = 0; kk < 8; kk++) {
            float a[8], b[8];
            *(float4*)&a[0] = *(const float4*)&As[kk][ty * 8];
            *(float4*)&a[4] = *(const float4*)&As[kk][ty * 8 + 4];
            *(float4*)&b[0] = *(const float4*)&Bs[kk][tx * 8];
            *(float4*)&b[4] = *(const float4*)&Bs[kk][tx * 8 + 4];
            #pragma unroll
            for (int i = 0; i < 8; i++)
                #pragma unroll
                for (int j = 0; j < 8; j++)
                    acc[i][j] = fmaf(a[i], b[j], acc[i][j]);
        }
    }
    const int crow = by * 128 + ty * 8;
    const int ccol = bx * 128 + tx * 8;
    float bs[8];
    #pragma unroll
    for (int j = 0; j < 8; j++) bs[j] = bias[ccol + j];
    #pragma unroll
    for (int i = 0; i < 8; i++) {
        float4 o0, o1;
        o0.x = acc[i][0] + bs[0]; o0.y = acc[i][1] + bs[1];
        o0.z = acc[i][2] + bs[2]; o0.w = acc[i][3] + bs[3];
        o1.x = acc[i][4] + bs[4]; o1.y = acc[i][5] + bs[5];
        o1.z = acc[i][6] + bs[6]; o1.w = acc[i][7] + bs[7];
        *(float4*)(C + (size_t)(crow + i) * N + ccol)     = o0;
        *(float4*)(C + (size_t)(crow + i) * N + ccol + 4) = o1;
    }
}

__global__ __launch_bounds__(256) void rope_kernel(float* __restrict__ qkv,
                                                   const float* __restrict__ rope) {
    const int s = blockIdx.x;
    for (int idx = threadIdx.x; idx < NH * 40; idx += 256) {
        const int hh = idx / 40, j = idx % 40;
        const float f  = rope[(size_t)s * 40 + j];
        const float cs = cosf(f), sn = sinf(f);
        size_t base = (size_t)s * QKV_N + hh * HD;
        float q0 = qkv[base + j], q1 = qkv[base + j + 40];
        qkv[base + j]      = q0 * cs - q1 * sn;
        qkv[base + j + 40] = q1 * cs + q0 * sn;
        size_t kb = base + DIM;
        float k0 = qkv[kb + j], k1 = qkv[kb + j + 40];
        qkv[kb + j]      = k0 * cs - k1 * sn;
        qkv[kb + j + 40] = k1 * cs + k0 * sn;
    }
}

__global__ __launch_bounds__(256) void attn_flash(const float* __restrict__ qkv,
                                                  const int* __restrict__ cu,
                                                  float* __restrict__ aout) {
    __shared__ float Qs[80][68];
    __shared__ float Ks[80][68];
    __shared__ float Vs[64][80];
    float* Ps = &Ks[0][0];
    const int hh  = blockIdx.x;
    const int qt  = blockIdx.y;
    const int tid = threadIdx.x;
    const int tx  = tid & 15;
    const int ty  = tid >> 4;
    const int q0  = qt * 64;
    int c0 = cu[0], c1 = cu[1], c2 = cu[2], c3 = cu[3], c4 = cu[4];
    auto seg = [&](int r, int& s, int& e) {
        if      (r < c1) { s = c0; e = c1; }
        else if (r < c2) { s = c1; e = c2; }
        else if (r < c3) { s = c2; e = c3; }
        else             { s = c3; e = c4; }
    };
    int rs[4], re[4];
    #pragma unroll
    for (int i = 0; i < 4; i++) seg(q0 + ty * 4 + i, rs[i], re[i]);
    int kstart, kend;
    { int s, e; seg(q0, s, e); kstart = s; seg(q0 + 63, s, e); kend = e; }
    for (int i2 = tid; i2 < 64 * 20; i2 += 256) {
        int r = i2 / 20, c4f = (i2 % 20) * 4;
        float4 v = *(const float4*)(qkv + (size_t)(q0 + r) * QKV_N + hh * HD + c4f);
        Qs[c4f + 0][r] = v.x; Qs[c4f + 1][r] = v.y;
        Qs[c4f + 2][r] = v.z; Qs[c4f + 3][r] = v.w;
    }
    float m_[4], l_[4], o_[4][5];
    #pragma unroll
    for (int i = 0; i < 4; i++) {
        m_[i] = -3.0e38f; l_[i] = 0.f;
        #pragma unroll
        for (int d = 0; d < 5; d++) o_[i][d] = 0.f;
    }
    const float scale = 0.11180339887498949f;
    for (int k0 = kstart; k0 < kend; k0 += 64) {
        __syncthreads();
        for (int i2 = tid; i2 < 64 * 20; i2 += 256) {
            int r = i2 / 20, c4f = (i2 % 20) * 4;
            int kk = k0 + r;
            float4 kv, vv;
            if (kk < kend) {
                kv = *(const float4*)(qkv + (size_t)kk * QKV_N + DIM     + hh * HD + c4f);
                vv = *(const float4*)(qkv + (size_t)kk * QKV_N + 2 * DIM + hh * HD + c4f);
            } else {
                kv = make_float4(0.f, 0.f, 0.f, 0.f); vv = kv;
            }
            Ks[c4f + 0][r] = kv.x; Ks[c4f + 1][r] = kv.y;
            Ks[c4f + 2][r] = kv.z; Ks[c4f + 3][r] = kv.w;
            *(float4*)&Vs[r][c4f] = vv;
        }
        __syncthreads();
        float s4[4][4];
        #pragma unroll
        for (int i = 0; i < 4; i++)
            #pragma unroll
            for (int j = 0; j < 4; j++) s4[i][j] = 0.f;
        for (int d = 0; d < 80; d++) {
            float4 qv = *(const float4*)&Qs[d][ty * 4];
            float4 kv = *(const float4*)&Ks[d][tx * 4];
            float qa[4] = {qv.x, qv.y, qv.z, qv.w};
            float ka[4] = {kv.x, kv.y, kv.z, kv.w};
            #pragma unroll
            for (int i = 0; i < 4; i++)
                #pragma unroll
                for (int j = 0; j < 4; j++)
                    s4[i][j] = fmaf(qa[i], ka[j], s4[i][j]);
        }
        float p[4][4];
        #pragma unroll
        for (int i = 0; i < 4; i++) {
            float mt = -3.0e38f;
            #pragma unroll
            for (int j = 0; j < 4; j++) {
                int kk = k0 + tx * 4 + j;
                bool valid = (kk >= rs[i]) && (kk < re[i]);
                s4[i][j] = valid ? s4[i][j] * scale : -3.0e38f;
                mt = fmaxf(mt, s4[i][j]);
            }
            #pragma unroll
            for (int off = 1; off < 16; off <<= 1)
                mt = fmaxf(mt, __shfl_xor(mt, off, 64));
            float mn = fmaxf(m_[i], mt);
            float al = __expf(m_[i] - mn);
            float lt = 0.f;
            #pragma unroll
            for (int j = 0; j < 4; j++) {
                p[i][j] = (s4[i][j] > -1.0e38f) ? __expf(s4[i][j] - mn) : 0.f;
                lt += p[i][j];
            }
            #pragma unroll
            for (int off = 1; off < 16; off <<= 1)
                lt += __shfl_xor(lt, off, 64);
            l_[i] = l_[i] * al + lt;
            m_[i] = mn;
            #pragma unroll
            for (int dd = 0; dd < 5; dd++) o_[i][dd] *= al;
        }
        __syncthreads();
        #pragma unroll
        for (int i = 0; i < 4; i++)
            *(float4*)&Ps[(size_t)(ty * 4 + i) * 68 + tx * 4] =
                make_float4(p[i][0], p[i][1], p[i][2], p[i][3]);
        __syncthreads();
        for (int k = 0; k < 64; k++) {
            float vv[5];
            #pragma unroll
            for (int dd = 0; dd < 5; dd++) vv[dd] = Vs[k][tx * 5 + dd];
            #pragma unroll
            for (int i = 0; i < 4; i++) {
                float pv = Ps[(size_t)(ty * 4 + i) * 68 + k];
                #pragma unroll
                for (int dd = 0; dd < 5; dd++)
                    o_[i][dd] = fmaf(pv, vv[dd], o_[i][dd]);
            }
        }
    }
    #pragma unroll
    for (int i = 0; i < 4; i++) {
        float inv = 1.0f / l_[i];
        #pragma unroll
        for (int dd = 0; dd < 5; dd++)
            aout[(size_t)(q0 + ty * 4 + i) * DIM + hh * HD + tx * 5 + dd] = o_[i][dd] * inv;
    }
}

// ---------------------------------------------------------------------------
extern "C" void kernel_launch(void* const* d_in, const int* in_sizes, int n_in,
                              void* d_out, int out_size, void* d_ws, size_t ws_size,
                              hipStream_t stream) {
    const float* hidden = (const float*)d_in[0];
    const int*   cu     = (const int*)d_in[1];
    const float* rope   = (const float*)d_in[2];
    const float* qkv_w  = (const float*)d_in[3];
    const float* qkv_b  = (const float*)d_in[4];
    const float* proj_w = (const float*)d_in[5];
    const float* proj_b = (const float*)d_in[6];
    float* out = (float*)d_out;

    char* ws = (char*)d_ws;
    const size_t need = 80609280;

    if (ws_size >= need) {
        // layout (bytes):
        //   qkvQK f32 [S][2560] @0         (31457280)   - written by gemm1
        //   Vt  bf16 [1280][S]  @31457280  (7864320)    - written by gemm1 (fused)
        //   Wt  bf16 [3840][1280] @39321600 (9830400)   - gemm1 weights
        //   Hh  @49152000, Hl @57016320                 - gemm1 A planes
        //   Qh @64880640, Ql @72744960                  - rope outputs (ends 80609280)
        //   Kh @39321600 (over Wt, dead after gemm1)
        //   Pt @23592960 (over qkvQK, dead after rope_split)
        //   Oh @7864320  (over qkvQK, dead after rope_split)
        float* qkvQK = (float*)ws;
        u16* Vt = (u16*)(ws + 31457280);
        u16* Wt = (u16*)(ws + 39321600);
        u16* Hh = (u16*)(ws + 49152000);
        u16* Hl = (u16*)(ws + 57016320);
        u16* Qh = (u16*)(ws + 64880640);
        u16* Ql = (u16*)(ws + 72744960);
        u16* Kh = (u16*)(ws + 39321600);
        u16* Pt = (u16*)(ws + 23592960);
        u16* Oh = (u16*)(ws + 7864320);

        split_rows<<<2048, 256, 0, stream>>>(hidden, Hh, Hl, SEQ * DIM / 4);
        transpose_w<<<dim3(QKV_N / 32, DIM / 32), 256, 0, stream>>>(
            qkv_w, Wt, DIM, QKV_N);
        // gemm1: Q cols (bn<10) 2-stream -> f32; K cols (10..19) 1-stream -> f32;
        //        V cols (20..29) 1-stream -> fused transposed bf16 Vt
        gemm_fused<<<(QKV_N / 128) * (SEQ / 128), 256, 0, stream>>>(
            Hh, Hl, Wt, qkv_b, qkvQK, 2560, Vt, 10, 20,
            QKV_N / 128, SEQ, QKV_N, DIM);
        rope_split_qk<<<SEQ, 256, 0, stream>>>(qkvQK, rope, Qh, Ql, Kh);
        transpose_w<<<dim3(DIM / 32, DIM / 32), 256, 0, stream>>>(
            proj_w, Pt, DIM, DIM);
        attn_mfma3<<<dim3(NH, SEQ / 128), 512, 0, stream>>>(
            Qh, Ql, Kh, Vt, cu, Oh);
        // gemm2: single-stream (Oh only), all f32 out
        gemm_fused<<<(DIM / 128) * (SEQ / 128), 256, 0, stream>>>(
            Oh, nullptr, Pt, proj_b, out, DIM, nullptr, 0, DIM / 128,
            DIM / 128, SEQ, DIM, DIM);
    } else {
        // f32 fallback
        float* qkv  = (float*)ws;
        float* aout = qkv + (size_t)SEQ * QKV_N;
        sgemm_bias<<<dim3(QKV_N / 128, SEQ / 128), 256, 0, stream>>>(
            hidden, qkv_w, qkv_b, qkv, SEQ, QKV_N, DIM);
        rope_kernel<<<SEQ, 256, 0, stream>>>(qkv, rope);
        attn_flash<<<dim3(NH, SEQ / 64), 256, 0, stream>>>(qkv, cu, aout);
        sgemm_bias<<<dim3(DIM / 128, SEQ / 128), 256, 0, stream>>>(
            aout, proj_w, proj_b, out, SEQ, DIM, DIM);
    }
}

// Round 8
// 248.387 us; speedup vs baseline: 1.2343x; 1.2343x over previous
//
#include <hip/hip_runtime.h>
#include <hip/hip_bf16.h>
#include <math.h>

#define SEQ   3072
#define DIM   1280
#define NH    16
#define HD    80
#define QKV_N 3840

typedef unsigned short u16;
typedef unsigned int   u32;
typedef __attribute__((ext_vector_type(8))) short short8;   // 8 bf16 (4 VGPR)
typedef __attribute__((ext_vector_type(4))) short short4v;  // 4 bf16 (2 VGPR)
typedef __attribute__((ext_vector_type(4))) float f32x4;    // MFMA accumulator

#if defined(__has_builtin)
#  if __has_builtin(__builtin_amdgcn_mfma_f32_16x16x16bf16_1k)
#    define MFMA16(a,b,c) __builtin_amdgcn_mfma_f32_16x16x16bf16_1k(a,b,c,0,0,0)
#  endif
#endif
#ifndef MFMA16
__device__ __forceinline__ f32x4 mfma16_asm(short4v a, short4v b, f32x4 c) {
    f32x4 d;
    asm volatile("v_mfma_f32_16x16x16_bf16 %0, %1, %2, %3"
                 : "=v"(d) : "v"(a), "v"(b), "0"(c));
    return d;
}
#  define MFMA16(a,b,c) mfma16_asm(a,b,c)
#endif

// ---------------------------------------------------------------------------
// f32 -> bf16 (RTNE) and hi/lo split
// ---------------------------------------------------------------------------
__device__ __forceinline__ u16 f32_to_bf16(float x) {
    unsigned xb = __float_as_uint(x);
    return (u16)((xb + 0x7fffu + ((xb >> 16) & 1u)) >> 16);
}
__device__ __forceinline__ void split1(float x, u16& h, u16& l) {
    h = f32_to_bf16(x);
    float hf = __uint_as_float(((unsigned)h) << 16);
    l = f32_to_bf16(x - hf);
}
__device__ __forceinline__ u32 pack2(float a, float b) {
    return (u32)f32_to_bf16(a) | ((u32)f32_to_bf16(b) << 16);
}

__device__ __forceinline__ void gload16(const void* g, void* l) {
    __builtin_amdgcn_global_load_lds(
        (const __attribute__((address_space(1))) void*)g,
        (__attribute__((address_space(3))) void*)l, 16, 0, 0);
}

// ---------------------------------------------------------------------------
// split_rows: f32[n] -> hi bf16[n], lo bf16[n]
// ---------------------------------------------------------------------------
__global__ __launch_bounds__(256) void split_rows(const float* __restrict__ in,
                                                  u16* __restrict__ oh,
                                                  u16* __restrict__ ol, int n4) {
    int i = blockIdx.x * 256 + threadIdx.x;
    int stride = gridDim.x * 256;
    for (; i < n4; i += stride) {
        float4 v = ((const float4*)in)[i];
        ushort4 h, l;
        split1(v.x, h.x, l.x); split1(v.y, h.y, l.y);
        split1(v.z, h.z, l.z); split1(v.w, h.w, l.w);
        ((ushort4*)oh)[i] = h; ((ushort4*)ol)[i] = l;
    }
}

// ---------------------------------------------------------------------------
// transpose_w: in f32 [K][N] -> o bf16 [N][K]  (hi only)
// ---------------------------------------------------------------------------
__global__ __launch_bounds__(256) void transpose_w(const float* __restrict__ in,
                                                   u16* __restrict__ o,
                                                   int K, int N) {
    __shared__ float t[32][33];
    const int n0 = blockIdx.x * 32, k0 = blockIdx.y * 32;
    const int tx = threadIdx.x & 31, ty = threadIdx.x >> 5;  // 32 x 8
    #pragma unroll
    for (int j = 0; j < 4; j++)
        t[ty + j * 8][tx] = in[(size_t)(k0 + ty + j * 8) * N + n0 + tx];
    __syncthreads();
    #pragma unroll
    for (int j = 0; j < 4; j++)
        o[(size_t)(n0 + ty + j * 8) * K + k0 + tx] = f32_to_bf16(t[tx][ty + j * 8]);
}

// ---------------------------------------------------------------------------
// Templated MFMA GEMM (compile-time stream count -> registers, full unroll):
//   LO=true : C = (Ah+Al) @ Bh^T + bias   (3 LDS planes, 24 chunks, 6/wave)
//   LO=false: C =  Ah     @ Bh^T + bias   (2 LDS planes, 16 chunks, 4/wave)
// 128x128 tile, BK=32, 4 waves, LDS dbuf, proven 2-phase sync.
// Epilogue: bn < bn_f32 -> f32 to Cf (stride ldc, pre-offset by launch);
//           else transposed bf16 to Vt[col - bn_f32*128][row].
// 1-D grid (nbn x M/128), bijective XCD-chunked swizzle, bm-major.
// ---------------------------------------------------------------------------
template <bool LO>
__global__ __launch_bounds__(256) void gemm_t(const u16* __restrict__ Ah,
                                              const u16* __restrict__ Al,
                                              const u16* __restrict__ Bh,
                                              const float* __restrict__ bias,
                                              float* __restrict__ Cf, int ldc,
                                              u16* __restrict__ Vt, int bn_f32,
                                              int nbn, int M, int K) {
    constexpr int NC   = LO ? 6 : 4;          // staging chunks per wave
    constexpr int NW   = LO ? 12288 : 8192;   // LDS u16 words per buffer
    constexpr int BOFF = LO ? 16384 : 8192;   // B plane byte offset
    __shared__ u16 lds[2][NW];
    const int tid  = threadIdx.x;
    const int lane = tid & 63;
    const int w    = tid >> 6;

    // bijective XCD swizzle
    const int nwg = gridDim.x;
    const int qd  = nwg >> 3, rm = nwg & 7;
    const int xcd = blockIdx.x & 7, idx = blockIdx.x >> 3;
    const int wg  = (xcd < rm ? xcd * (qd + 1) : rm * (qd + 1) + (xcd - rm) * qd) + idx;
    const int bm = wg / nbn, bn = wg - bm * nbn;
    const int wm = w >> 1, wn = w & 1;

    const int rl   = lane >> 2;                      // row within 16-row seg
    const int slot = lane & 3;
    const int ks   = (slot ^ ((rl >> 1) & 3)) * 8;   // swizzled k elem offset

    const u16* Ablk = Ah + (size_t)(bm * 128) * K;
    const u16* Lblk = LO ? Al + (size_t)(bm * 128) * K : nullptr;
    const u16* Bblk = Bh + (size_t)(bn * 128) * K;

    const u16* csrc[NC];
    int cdst[NC];
    #pragma unroll
    for (int i = 0; i < NC; i++) {
        int c = w * NC + i, seg = c & 7;
        int p = LO ? (c >> 3) : ((c >> 3) ? 2 : 0);  // plane id 0:A 1:Al 2:B
        const u16* base = (p == 0) ? Ablk : (p == 1) ? Lblk : Bblk;
        csrc[i] = base + (size_t)(seg * 16 + rl) * K + ks;
        cdst[i] = (LO ? p : (p ? 1 : 0)) * 4096 + seg * 512;   // u16 index
    }

    const f32x4 zero = {0.f, 0.f, 0.f, 0.f};
    f32x4 acc[4][4];
    #pragma unroll
    for (int i = 0; i < 4; i++)
        #pragma unroll
        for (int j = 0; j < 4; j++) acc[i][j] = zero;

    const int r16 = lane & 15, kg = lane >> 4;
    const int sw  = (kg ^ ((r16 >> 1) & 3)) * 16;    // swizzled byte slot for reads

    const int nt = K >> 5;   // BK=32 steps

    // prologue: stage tile 0 into buf 0
    #pragma unroll
    for (int i = 0; i < NC; i++)
        gload16(csrc[i], &lds[0][cdst[i]]);
    __syncthreads();

    int cur = 0;
    for (int t = 0; t < nt; t++) {
        if (t + 1 < nt) {                 // prefetch next tile into other buffer
            #pragma unroll
            for (int i = 0; i < NC; i++)
                gload16(csrc[i] + (t + 1) * 32, &lds[cur ^ 1][cdst[i]]);
        }

        const char* ldsb = (const char*)&lds[cur][0];
        short8 ah[4], al[4], bh[4];
        #pragma unroll
        for (int i = 0; i < 4; i++) {
            int offA = (wm * 64 + i * 16 + r16) * 64 + sw;
            ah[i] = *(const short8*)(ldsb + offA);
            if (LO) al[i] = *(const short8*)(ldsb + 8192 + offA);
            int offB = (wn * 64 + i * 16 + r16) * 64 + sw;
            bh[i] = *(const short8*)(ldsb + BOFF + offB);
        }
        #pragma unroll
        for (int i = 0; i < 4; i++)
            #pragma unroll
            for (int j = 0; j < 4; j++) {
                acc[i][j] = __builtin_amdgcn_mfma_f32_16x16x32_bf16(ah[i], bh[j], acc[i][j], 0, 0, 0);
                if (LO)
                    acc[i][j] = __builtin_amdgcn_mfma_f32_16x16x32_bf16(al[i], bh[j], acc[i][j], 0, 0, 0);
            }

        __syncthreads();   // drains vmcnt + lgkm; gates buffer swap
        cur ^= 1;
    }

    const int rg = lane >> 4;
    #pragma unroll
    for (int j = 0; j < 4; j++) {
        int col = bn * 128 + wn * 64 + j * 16 + r16;
        float bv = bias[col];
        #pragma unroll
        for (int i = 0; i < 4; i++) {
            int row0 = bm * 128 + wm * 64 + i * 16 + rg * 4;
            if (bn < bn_f32) {
                #pragma unroll
                for (int r = 0; r < 4; r++)
                    Cf[(size_t)(row0 + r) * ldc + col] = acc[i][j][r] + bv;
            } else {
                // V region: write transposed bf16 Vt[vcol][row], 4 rows contiguous
                int vcol = col - bn_f32 * 128;
                short4v hv;
                #pragma unroll
                for (int r = 0; r < 4; r++)
                    hv[r] = (short)f32_to_bf16(acc[i][j][r] + bv);
                *(short4v*)(Vt + (size_t)vcol * M + row0) = hv;
            }
        }
    }
}

// ---------------------------------------------------------------------------
// rope_split_qk: qk f32 [S][2560] + rope -> Qh/Ql (scaled by 1/sqrt(80)),
// Kh bf16 [S][1280]
// ---------------------------------------------------------------------------
__global__ __launch_bounds__(256) void rope_split_qk(const float* __restrict__ qk,
                                                     const float* __restrict__ rope,
                                                     u16* __restrict__ Qh, u16* __restrict__ Ql,
                                                     u16* __restrict__ Kh) {
    __shared__ float cs[40], sn[40];
    const int s = blockIdx.x;
    if (threadIdx.x < 40) {
        float f = rope[(size_t)s * 40 + threadIdx.x];
        cs[threadIdx.x] = cosf(f);
        sn[threadIdx.x] = sinf(f);
    }
    __syncthreads();
    const float qs = 0.11180339887498949f;   // 1/sqrt(80)
    const size_t ib = (size_t)s * 2560;
    const size_t ob = (size_t)s * DIM;
    for (int p = threadIdx.x; p < 640; p += 256) {
        int hh = p / 40, j = p - hh * 40;
        float c = cs[j], sv = sn[j];
        int e0 = hh * 80 + j, e1 = e0 + 40;
        float a0 = qk[ib + e0], a1 = qk[ib + e1];
        u16 x, y;
        split1((a0 * c - a1 * sv) * qs, x, y); Qh[ob + e0] = x; Ql[ob + e0] = y;
        split1((a1 * c + a0 * sv) * qs, x, y); Qh[ob + e1] = x; Ql[ob + e1] = y;
        float b0 = qk[ib + 1280 + e0], b1 = qk[ib + 1280 + e1];
        Kh[ob + e0] = f32_to_bf16(b0 * c - b1 * sv);
        Kh[ob + e1] = f32_to_bf16(b1 * c + b0 * sv);
    }
}

// ---------------------------------------------------------------------------
// MFMA flash attention v3: QBLK=128, 8 waves (512 thr).
//  - swapped QK^T: acc[key][q]; softmax in-register (lane owns q-row r16)
//  - PV via 16x16x16 MFMA with packed-P B-frag (no cross-lane P movement)
//  - global_load_lds staging (3 chunks/wave), dbuf, counted vmcnt(3)
// ---------------------------------------------------------------------------
__global__ __launch_bounds__(512) void attn_mfma3(const u16* __restrict__ Qh,
                                                  const u16* __restrict__ Ql,
                                                  const u16* __restrict__ Kh,
                                                  const u16* __restrict__ Vt,
                                                  const int* __restrict__ cu,
                                                  u16* __restrict__ Oh) {
    __shared__ u16 lds[2][12288];   // per buf: K [64][80] =10240B, V [80][80]+slack
    const int tid  = threadIdx.x;
    const int lane = tid & 63;
    const int w    = tid >> 6;       // 0..7
    const int r16  = lane & 15;
    const int kg   = lane >> 4;
    const int h    = blockIdx.x;
    const int q0   = blockIdx.y * 128;

    int kstart, kend;
    {
        int c1 = cu[1], c2 = cu[2], c3 = cu[3];
        if      (q0 < c1) { kstart = cu[0]; kend = c1; }
        else if (q0 < c2) { kstart = c1;    kend = c2; }
        else if (q0 < c3) { kstart = c2;    kend = c3; }
        else              { kstart = c3;    kend = cu[4]; }
    }

    // per-lane global staging sources: 3 chunks (1 KB each) per wave, 24 total
    const char* cbase[3];
    int cscale[3];
    #pragma unroll
    for (int i = 0; i < 3; i++) {
        int c = w * 3 + i;
        if (c < 10) {                        // K plane: [64 rows][160 B]
            int o = c * 1024 + lane * 16;
            int row = o / 160, col = o - row * 160;
            cbase[i]  = (const char*)Kh + (size_t)row * 2560 + h * 160 + col;
            cscale[i] = 2560;                // + k0 rows
        } else {                             // V plane: [80 rows][160 B] + slack
            int o = (c - 10) * 1024 + lane * 16;
            int row = o / 160, col = o - row * 160;
            if (row > 79) row = 79;          // slack lanes: clamp to a safe row
            cbase[i]  = (const char*)Vt + (size_t)(h * HD + row) * (SEQ * 2) + col;
            cscale[i] = 2;                   // + k0 elems
        }
    }

    // Q fragments (pre-scaled); B-operand of swapped QK^T
    const short8 z8 = {0, 0, 0, 0, 0, 0, 0, 0};
    short8 qfh[3], qfl[3];
    {
        const size_t qb = (size_t)(q0 + w * 16 + r16) * DIM + h * HD;
        #pragma unroll
        for (int ks = 0; ks < 3; ks++) {
            int ko = ks * 32 + kg * 8;
            if (ko < HD) {
                qfh[ks] = *(const short8*)(Qh + qb + ko);
                qfl[ks] = *(const short8*)(Ql + qb + ko);
            } else { qfh[ks] = z8; qfl[ks] = z8; }
        }
    }

    const f32x4 zf = {0.f, 0.f, 0.f, 0.f};
    f32x4 acc_o[5] = {zf, zf, zf, zf, zf};   // O^T: lane q-row = r16, d = db*16+kg*4+r
    float m_ = -3.0e38f, l_ = 0.f;

    // prologue stage of first tile
    {
        char* dst = (char*)&lds[0][0] + (w * 3) * 1024;
        #pragma unroll
        for (int i = 0; i < 3; i++)
            gload16(cbase[i] + (size_t)kstart * cscale[i], dst + i * 1024);
    }

    int cur = 0;
    for (int k0 = kstart; k0 < kend; k0 += 64) {
        if (k0 + 64 < kend) {                // prefetch next tile into other buffer
            char* dst = (char*)&lds[cur ^ 1][0] + (w * 3) * 1024;
            #pragma unroll
            for (int i = 0; i < 3; i++)
                gload16(cbase[i] + (size_t)(k0 + 64) * cscale[i], dst + i * 1024);
            __builtin_amdgcn_sched_barrier(0);
            asm volatile("s_waitcnt vmcnt(3)");   // drain current tile, keep 3 in flight
        } else {
            __builtin_amdgcn_sched_barrier(0);
            asm volatile("s_waitcnt vmcnt(0)");
        }
        __builtin_amdgcn_s_barrier();
        __builtin_amdgcn_sched_barrier(0);

        const char* bK = (const char*)&lds[cur][0];
        const char* bV = bK + 10240;

        // ---- QK^T (swapped): accs[kb] = C[key-sub][q=r16], key = kb*16+kg*4+r
        f32x4 accs[4] = {zf, zf, zf, zf};
        #pragma unroll
        for (int kb = 0; kb < 4; kb++) {
            #pragma unroll
            for (int ks = 0; ks < 3; ks++) {
                short8 af = *(const short8*)(bK + (kb * 16 + r16) * 160 + ks * 64 + kg * 16);
                accs[kb] = __builtin_amdgcn_mfma_f32_16x16x32_bf16(af, qfh[ks], accs[kb], 0, 0, 0);
                accs[kb] = __builtin_amdgcn_mfma_f32_16x16x32_bf16(af, qfl[ks], accs[kb], 0, 0, 0);
            }
        }

        // ---- online softmax (scores pre-scaled); lane owns q-row r16
        float tmax = -3.0e38f;
        #pragma unroll
        for (int kb = 0; kb < 4; kb++)
            tmax = fmaxf(tmax, fmaxf(fmaxf(accs[kb][0], accs[kb][1]),
                                     fmaxf(accs[kb][2], accs[kb][3])));
        tmax = fmaxf(tmax, __shfl_xor(tmax, 16, 64));
        tmax = fmaxf(tmax, __shfl_xor(tmax, 32, 64));
        float mn = fmaxf(m_, tmax);
        float al = __expf(m_ - mn);
        float lt = 0.f;
        u32 pk[4][2];
        #pragma unroll
        for (int kb = 0; kb < 4; kb++) {
            float p0 = __expf(accs[kb][0] - mn);
            float p1 = __expf(accs[kb][1] - mn);
            float p2 = __expf(accs[kb][2] - mn);
            float p3 = __expf(accs[kb][3] - mn);
            lt += (p0 + p1) + (p2 + p3);
            pk[kb][0] = pack2(p0, p1);
            pk[kb][1] = pack2(p2, p3);
        }
        lt += __shfl_xor(lt, 16, 64);
        lt += __shfl_xor(lt, 32, 64);
        l_ = l_ * al + lt;
        m_ = mn;
        #pragma unroll
        for (int db = 0; db < 5; db++) acc_o[db] *= al;

        // ---- PV (16x16x16): A = Vt rows (d), B = packed P (direct reg reuse)
        #pragma unroll
        for (int kb = 0; kb < 4; kb++) {
            union { u32 u[2]; short4v s; } cv;
            cv.u[0] = pk[kb][0]; cv.u[1] = pk[kb][1];
            short4v pb = cv.s;
            #pragma unroll
            for (int db = 0; db < 5; db++) {
                short4v vf = *(const short4v*)(bV + (db * 16 + r16) * 160 + kb * 32 + kg * 8);
                acc_o[db] = MFMA16(vf, pb, acc_o[db]);
            }
        }

        __builtin_amdgcn_s_barrier();        // all reads of buf[cur] done
        __builtin_amdgcn_sched_barrier(0);
        cur ^= 1;
    }

    // ---- epilogue: O^T -> Oh [S][1280]; lane q-row = r16 (hi plane only)
    float inv = 1.0f / l_;
    const size_t ob = (size_t)(q0 + w * 16 + r16) * DIM + h * HD + kg * 4;
    #pragma unroll
    for (int db = 0; db < 5; db++) {
        short4v hv;
        #pragma unroll
        for (int r = 0; r < 4; r++)
            hv[r] = (short)f32_to_bf16(acc_o[db][r] * inv);
        *(short4v*)(Oh + ob + db * 16) = hv;
    }
}

// ---------------------------------------------------------------------------
// f32 fallback path (round-1, known-good)
// ---------------------------------------------------------------------------
__global__ __launch_bounds__(256) void sgemm_bias(const float* __restrict__ A,
                                                  const float* __restrict__ B,
                                                  const float* __restrict__ bias,
                                                  float* __restrict__ C,
                                                  int M, int N, int K) {
    __shared__ float As[8][128];
    __shared__ float Bs[8][128];
    const int tid = threadIdx.x;
    const int tx  = tid & 15;
    const int ty  = tid >> 4;
    const int bx  = blockIdx.x, by = blockIdx.y;
    const int row_a = tid >> 1;
    const int col_a = (tid & 1) * 4;
    const int row_b = tid >> 5;
    const int col_b = (tid & 31) * 4;
    const float* Ap = A + (size_t)(by * 128 + row_a) * K + col_a;
    const float* Bp = B + (size_t)row_b * N + bx * 128 + col_b;
    float acc[8][8];
    #pragma unroll
    for (int i = 0; i < 8; i++)
        #pragma unroll
        for (int j = 0; j < 8; j++) acc[i][j] = 0.f;
    for (int k0 = 0; k0 < K; k0 += 8) {
        float4 av = *(const float4*)(Ap + k0);
        float4 bv = *(const float4*)(Bp + (size_t)k0 * N);
        __syncthreads();
        As[col_a + 0][row_a] = av.x; As[col_a + 1][row_a] = av.y;
        As[col_a + 2][row_a] = av.z; As[col_a + 3][row_a] = av.w;
        *(float4*)&Bs[row_b][col_b] = bv;
        __syncthreads();
        #pragma unroll
        for (int kk = 0; kk < 8; kk++) {
            float a[8], b[8];
            *(float4*)&a[0] = *(const float4*)&As[kk][ty * 8];
            *(float4*)&a[4] = *(const float4*)&As[kk][ty * 8 + 4];
            *(float4*)&b[0] = *(const float4*)&Bs[kk][tx * 8];
            *(float4*)&b[4] = *(const float4*)&Bs[kk][tx * 8 + 4];
            #pragma unroll
            for (int i = 0; i < 8; i++)
                #pragma unroll
                for (int j = 0; j < 8; j++)
                    acc[i][j] = fmaf(a[i], b[j], acc[i][j]);
        }
    }
    const int crow = by * 128 + ty * 8;
    const int ccol = bx * 128 + tx * 8;
    float bs[8];
    #pragma unroll
    for (int j = 0; j < 8; j++) bs[j] = bias[ccol + j];
    #pragma unroll
    for (int i = 0; i < 8; i++) {
        float4 o0, o1;
        o0.x = acc[i][0] + bs[0]; o0.y = acc[i][1] + bs[1];
        o0.z = acc[i][2] + bs[2]; o0.w = acc[i][3] + bs[3];
        o1.x = acc[i][4] + bs[4]; o1.y = acc[i][5] + bs[5];
        o1.z = acc[i][6] + bs[6]; o1.w = acc[i][7] + bs[7];
        *(float4*)(C + (size_t)(crow + i) * N + ccol)     = o0;
        *(float4*)(C + (size_t)(crow + i) * N + ccol + 4) = o1;
    }
}

__global__ __launch_bounds__(256) void rope_kernel(float* __restrict__ qkv,
                                                   const float* __restrict__ rope) {
    const int s = blockIdx.x;
    for (int idx = threadIdx.x; idx < NH * 40; idx += 256) {
        const int hh = idx / 40, j = idx % 40;
        const float f  = rope[(size_t)s * 40 + j];
        const float cs = cosf(f), sn = sinf(f);
        size_t base = (size_t)s * QKV_N + hh * HD;
        float q0 = qkv[base + j], q1 = qkv[base + j + 40];
        qkv[base + j]      = q0 * cs - q1 * sn;
        qkv[base + j + 40] = q1 * cs + q0 * sn;
        size_t kb = base + DIM;
        float k0 = qkv[kb + j], k1 = qkv[kb + j + 40];
        qkv[kb + j]      = k0 * cs - k1 * sn;
        qkv[kb + j + 40] = k1 * cs + k0 * sn;
    }
}

__global__ __launch_bounds__(256) void attn_flash(const float* __restrict__ qkv,
                                                  const int* __restrict__ cu,
                                                  float* __restrict__ aout) {
    __shared__ float Qs[80][68];
    __shared__ float Ks[80][68];
    __shared__ float Vs[64][80];
    float* Ps = &Ks[0][0];
    const int hh  = blockIdx.x;
    const int qt  = blockIdx.y;
    const int tid = threadIdx.x;
    const int tx  = tid & 15;
    const int ty  = tid >> 4;
    const int q0  = qt * 64;
    int c0 = cu[0], c1 = cu[1], c2 = cu[2], c3 = cu[3], c4 = cu[4];
    auto seg = [&](int r, int& s, int& e) {
        if      (r < c1) { s = c0; e = c1; }
        else if (r < c2) { s = c1; e = c2; }
        else if (r < c3) { s = c2; e = c3; }
        else             { s = c3; e = c4; }
    };
    int rs[4], re[4];
    #pragma unroll
    for (int i = 0; i < 4; i++) seg(q0 + ty * 4 + i, rs[i], re[i]);
    int kstart, kend;
    { int s, e; seg(q0, s, e); kstart = s; seg(q0 + 63, s, e); kend = e; }
    for (int i2 = tid; i2 < 64 * 20; i2 += 256) {
        int r = i2 / 20, c4f = (i2 % 20) * 4;
        float4 v = *(const float4*)(qkv + (size_t)(q0 + r) * QKV_N + hh * HD + c4f);
        Qs[c4f + 0][r] = v.x; Qs[c4f + 1][r] = v.y;
        Qs[c4f + 2][r] = v.z; Qs[c4f + 3][r] = v.w;
    }
    float m_[4], l_[4], o_[4][5];
    #pragma unroll
    for (int i = 0; i < 4; i++) {
        m_[i] = -3.0e38f; l_[i] = 0.f;
        #pragma unroll
        for (int d = 0; d < 5; d++) o_[i][d] = 0.f;
    }
    const float scale = 0.11180339887498949f;
    for (int k0 = kstart; k0 < kend; k0 += 64) {
        __syncthreads();
        for (int i2 = tid; i2 < 64 * 20; i2 += 256) {
            int r = i2 / 20, c4f = (i2 % 20) * 4;
            int kk = k0 + r;
            float4 kv, vv;
            if (kk < kend) {
                kv = *(const float4*)(qkv + (size_t)kk * QKV_N + DIM     + hh * HD + c4f);
                vv = *(const float4*)(qkv + (size_t)kk * QKV_N + 2 * DIM + hh * HD + c4f);
            } else {
                kv = make_float4(0.f, 0.f, 0.f, 0.f); vv = kv;
            }
            Ks[c4f + 0][r] = kv.x; Ks[c4f + 1][r] = kv.y;
            Ks[c4f + 2][r] = kv.z; Ks[c4f + 3][r] = kv.w;
            *(float4*)&Vs[r][c4f] = vv;
        }
        __syncthreads();
        float s4[4][4];
        #pragma unroll
        for (int i = 0; i < 4; i++)
            #pragma unroll
            for (int j = 0; j < 4; j++) s4[i][j] = 0.f;
        for (int d = 0; d < 80; d++) {
            float4 qv = *(const float4*)&Qs[d][ty * 4];
            float4 kv = *(const float4*)&Ks[d][tx * 4];
            float qa[4] = {qv.x, qv.y, qv.z, qv.w};
            float ka[4] = {kv.x, kv.y, kv.z, kv.w};
            #pragma unroll
            for (int i = 0; i < 4; i++)
                #pragma unroll
                for (int j = 0; j < 4; j++)
                    s4[i][j] = fmaf(qa[i], ka[j], s4[i][j]);
        }
        float p[4][4];
        #pragma unroll
        for (int i = 0; i < 4; i++) {
            float mt = -3.0e38f;
            #pragma unroll
            for (int j = 0; j < 4; j++) {
                int kk = k0 + tx * 4 + j;
                bool valid = (kk >= rs[i]) && (kk < re[i]);
                s4[i][j] = valid ? s4[i][j] * scale : -3.0e38f;
                mt = fmaxf(mt, s4[i][j]);
            }
            #pragma unroll
            for (int off = 1; off < 16; off <<= 1)
                mt = fmaxf(mt, __shfl_xor(mt, off, 64));
            float mn = fmaxf(m_[i], mt);
            float al = __expf(m_[i] - mn);
            float lt = 0.f;
            #pragma unroll
            for (int j = 0; j < 4; j++) {
                p[i][j] = (s4[i][j] > -1.0e38f) ? __expf(s4[i][j] - mn) : 0.f;
                lt += p[i][j];
            }
            #pragma unroll
            for (int off = 1; off < 16; off <<= 1)
                lt += __shfl_xor(lt, off, 64);
            l_[i] = l_[i] * al + lt;
            m_[i] = mn;
            #pragma unroll
            for (int dd = 0; dd < 5; dd++) o_[i][dd] *= al;
        }
        __syncthreads();
        #pragma unroll
        for (int i = 0; i < 4; i++)
            *(float4*)&Ps[(size_t)(ty * 4 + i) * 68 + tx * 4] =
                make_float4(p[i][0], p[i][1], p[i][2], p[i][3]);
        __syncthreads();
        for (int k = 0; k < 64; k++) {
            float vv[5];
            #pragma unroll
            for (int dd = 0; dd < 5; dd++) vv[dd] = Vs[k][tx * 5 + dd];
            #pragma unroll
            for (int i = 0; i < 4; i++) {
                float pv = Ps[(size_t)(ty * 4 + i) * 68 + k];
                #pragma unroll
                for (int dd = 0; dd < 5; dd++)
                    o_[i][dd] = fmaf(pv, vv[dd], o_[i][dd]);
            }
        }
    }
    #pragma unroll
    for (int i = 0; i < 4; i++) {
        float inv = 1.0f / l_[i];
        #pragma unroll
        for (int dd = 0; dd < 5; dd++)
            aout[(size_t)(q0 + ty * 4 + i) * DIM + hh * HD + tx * 5 + dd] = o_[i][dd] * inv;
    }
}

// ---------------------------------------------------------------------------
extern "C" void kernel_launch(void* const* d_in, const int* in_sizes, int n_in,
                              void* d_out, int out_size, void* d_ws, size_t ws_size,
                              hipStream_t stream) {
    const float* hidden = (const float*)d_in[0];
    const int*   cu     = (const int*)d_in[1];
    const float* rope   = (const float*)d_in[2];
    const float* qkv_w  = (const float*)d_in[3];
    const float* qkv_b  = (const float*)d_in[4];
    const float* proj_w = (const float*)d_in[5];
    const float* proj_b = (const float*)d_in[6];
    float* out = (float*)d_out;

    char* ws = (char*)d_ws;
    const size_t need = 80609280;

    if (ws_size >= need) {
        // layout (bytes):
        //   qkvQK f32 [S][2560] @0         (31457280)   - gemm_q cols 0..1279,
        //                                                  gemm_kv K cols 1280..2559
        //   Vt  bf16 [1280][S]  @31457280  (7864320)    - gemm_kv fused V transpose
        //   Wt  bf16 [3840][1280] @39321600 (9830400)   - qkv weights^T
        //   Hh  @49152000, Hl @57016320                 - hidden hi/lo planes
        //   Qh @64880640, Ql @72744960                  - rope outputs (ends 80609280)
        //   Kh @39321600 (over Wt, dead after gemms)
        //   Pt @23592960 (over qkvQK tail, dead after rope_split)
        //   Oh @7864320  (over qkvQK,      dead after rope_split)
        float* qkvQK = (float*)ws;
        u16* Vt = (u16*)(ws + 31457280);
        u16* Wt = (u16*)(ws + 39321600);
        u16* Hh = (u16*)(ws + 49152000);
        u16* Hl = (u16*)(ws + 57016320);
        u16* Qh = (u16*)(ws + 64880640);
        u16* Ql = (u16*)(ws + 72744960);
        u16* Kh = (u16*)(ws + 39321600);
        u16* Pt = (u16*)(ws + 23592960);
        u16* Oh = (u16*)(ws + 7864320);

        split_rows<<<2048, 256, 0, stream>>>(hidden, Hh, Hl, SEQ * DIM / 4);
        transpose_w<<<dim3(QKV_N / 32, DIM / 32), 256, 0, stream>>>(
            qkv_w, Wt, DIM, QKV_N);
        // gemm_q: Q cols 0..1279, 2-stream, f32 out
        gemm_t<true><<<10 * (SEQ / 128), 256, 0, stream>>>(
            Hh, Hl, Wt, qkv_b, qkvQK, 2560, nullptr, 10, 10, SEQ, DIM);
        // gemm_kv: cols 1280..3839, 1-stream; K (local bn<10) -> f32,
        //          V (local bn 10..19) -> fused transposed bf16 Vt
        gemm_t<false><<<20 * (SEQ / 128), 256, 0, stream>>>(
            Hh, nullptr, Wt + (size_t)1280 * DIM, qkv_b + 1280,
            qkvQK + 1280, 2560, Vt, 10, 20, SEQ, DIM);
        rope_split_qk<<<SEQ, 256, 0, stream>>>(qkvQK, rope, Qh, Ql, Kh);
        transpose_w<<<dim3(DIM / 32, DIM / 32), 256, 0, stream>>>(
            proj_w, Pt, DIM, DIM);
        attn_mfma3<<<dim3(NH, SEQ / 128), 512, 0, stream>>>(
            Qh, Ql, Kh, Vt, cu, Oh);
        // gemm2: proj, 1-stream, all f32 out
        gemm_t<false><<<10 * (SEQ / 128), 256, 0, stream>>>(
            Oh, nullptr, Pt, proj_b, out, DIM, nullptr, 10, 10, SEQ, DIM);
    } else {
        // f32 fallback
        float* qkv  = (float*)ws;
        float* aout = qkv + (size_t)SEQ * QKV_N;
        sgemm_bias<<<dim3(QKV_N / 128, SEQ / 128), 256, 0, stream>>>(
            hidden, qkv_w, qkv_b, qkv, SEQ, QKV_N, DIM);
        rope_kernel<<<SEQ, 256, 0, stream>>>(qkv, rope);
        attn_flash<<<dim3(NH, SEQ / 64), 256, 0, stream>>>(qkv, cu, aout);
        sgemm_bias<<<dim3(DIM / 128, SEQ / 128), 256, 0, stream>>>(
            aout, proj_w, proj_b, out, SEQ, DIM, DIM);
    }
}